// Round 11
// baseline (13502.701 us; speedup 1.0000x reference)
//
#include <hip/hip_runtime.h>
#include <hip/hip_bf16.h>
#include <math.h>

#define BB 256
#define TT 512
#define INW 128
#define EH 512
#define GH 512

#define NGB 16           // blocks per group (column slices)
#define MG 16            // batch rows per group
#define NB 32            // output cols per block (2 x 16-col units)
#define FLS 16           // flag stride in u32 (64 B)

typedef __attribute__((ext_vector_type(8))) short bf16x8;
typedef __attribute__((ext_vector_type(4))) float f32x4;
typedef unsigned long long ull;

__device__ __forceinline__ float sigm(float x){ return 1.0f/(1.0f+__expf(-x)); }
__device__ __forceinline__ short f2bf(float x){
    __hip_bfloat16 h = __float2bfloat16(x);
    return *reinterpret_cast<short*>(&h);
}

// IC-coherent (agent-scope, relaxed) ops — the proven r3/r4/r9 data path
__device__ __forceinline__ ull ld_coh64(const ull* p){
    return __hip_atomic_load(p, __ATOMIC_RELAXED, __HIP_MEMORY_SCOPE_AGENT);
}
__device__ __forceinline__ void st_coh32(unsigned* p, unsigned v){
    __hip_atomic_store(p, v, __ATOMIC_RELAXED, __HIP_MEMORY_SCOPE_AGENT);
}
__device__ __forceinline__ unsigned ld_flag(const unsigned* p){
    return __hip_atomic_load(p, __ATOMIC_RELAXED, __HIP_MEMORY_SCOPE_AGENT);
}
__device__ __forceinline__ void wave_drain(){ asm volatile("s_waitcnt vmcnt(0)" ::: "memory"); }

// Stager (one wave): stage 16 units (16 cols x 16 rows, 512B each) from an
// exchange buffer into a swizzled LDS tile. Per unit: spin its producer-wave
// flag, then ISSUE loads immediately (pipelines under later spins); single
// drain at the end, then LDS writes. Skips this block's own units.
__device__ __forceinline__ void stage_units(
    const unsigned* fl, unsigned e, const char* gbase, size_t rowstride,
    char* sbuf, int b0, int lane, int u0, int ng)
{
    const int row = lane >> 2;
    const int bo  = (lane & 3) * 8;
    ull w[16];
    #pragma unroll
    for (int i = 0; i < 16; ++i){
        const int u = u0 + i;
        if ((u >> 1) != ng){
            const unsigned* fp = fl + u * FLS;
            long spins = 0;
            while (ld_flag(fp) < e){
                if (++spins > (1L << 20)) break;   // escape hatch
            }
            w[i] = ld_coh64((const ull*)(gbase + (size_t)(b0 + row)*rowstride + u*32 + bo));
        }
    }
    wave_drain();
    const int sw = (row & 7) << 4;
    #pragma unroll
    for (int i = 0; i < 16; ++i){
        const int u = u0 + i;
        if ((u >> 1) != ng){
            int kb = u*32 + bo;
            *(ull*)(sbuf + row*1024 + ((kb & ~15) ^ sw) + (kb & 15)) = w[i];
        }
    }
}

// publisher helper: pack lane-pair bf16 -> u32; even lane stores to IC AND to
// this block's own slice of the swizzled LDS tile (stagers skip own units)
__device__ __forceinline__ void pub_dual(unsigned* gdst, char* sbuf, int row,
                                         int gcol0 /*even col*/, unsigned mine, int l15)
{
    unsigned oth = __shfl_xor(mine, 1);
    if (!(l15 & 1)){
        unsigned pk = (oth << 16) | mine;
        st_coh32(gdst, pk);
        int kb = gcol0 * 2;
        *(unsigned*)(sbuf + row*1024 + ((kb & ~15) ^ ((row & 7) << 4)) + (kb & 15)) = pk;
    }
}

// ================= ENCODER =====================================================================
__global__ __launch_bounds__(512, 1) void enc_kernel(
    const float* __restrict__ src,   // [256][512][128]
    const float* __restrict__ Wi,    // [1536][128] rows r,z,n
    const float* __restrict__ Wh,    // [1536][512]
    short*       __restrict__ hbf,   // [2][256][512] bf16 ping-pong exchange
    float*       __restrict__ hencf, // [256][512] f32 final state
    unsigned*    __restrict__ flags) // [16 groups][32 units] x 64B
{
    __shared__ __align__(16) char sH[2][MG*1024];   // double-buffered h tile
    __shared__ __align__(16) char sX[2][MG*256];    // double-buffered x tile
    __shared__ float sR[MG*33], sZ[MG*33], sHfp[MG*33];

    const int bid = blockIdx.x, g = bid >> 4, ng = bid & 15;
    const int tid = threadIdx.x, wid = tid >> 6, lane = tid & 63;
    const int l15 = lane & 15, lk = lane >> 4;
    const int j0 = ng * NB, b0 = g * MG;
    const int gate = wid >> 1, ct = wid & 1, col = ct*16 + l15;
    unsigned* gf = flags + g * 32 * FLS;

    // persistent weights (r9-verified loader)
    bf16x8 whB[16], wxB[4];
    if (wid < 6){
        const float* wrh = Wh + (size_t)(gate*EH + j0 + col) * EH;
        const float* wrx = Wi + (size_t)(gate*EH + j0 + col) * INW;
        #pragma unroll
        for (int kt = 0; kt < 16; ++kt){
            int ke = kt*32 + lk*8;
            float4 f0 = *(const float4*)(wrh + ke);
            float4 f1 = *(const float4*)(wrh + ke + 4);
            bf16x8 v;
            v[0]=f2bf(f0.x); v[1]=f2bf(f0.y); v[2]=f2bf(f0.z); v[3]=f2bf(f0.w);
            v[4]=f2bf(f1.x); v[5]=f2bf(f1.y); v[6]=f2bf(f1.z); v[7]=f2bf(f1.w);
            whB[kt] = v;
        }
        #pragma unroll
        for (int kt = 0; kt < 4; ++kt){
            int ke = kt*32 + lk*8;
            float4 f0 = *(const float4*)(wrx + ke);
            float4 f1 = *(const float4*)(wrx + ke + 4);
            bf16x8 v;
            v[0]=f2bf(f0.x); v[1]=f2bf(f0.y); v[2]=f2bf(f0.z); v[3]=f2bf(f0.w);
            v[4]=f2bf(f1.x); v[5]=f2bf(f1.y); v[6]=f2bf(f1.z); v[7]=f2bf(f1.w);
            wxB[kt] = v;
        }
    }

    const int xrow = tid >> 4, xk = (tid & 15) * 8;   // x staging map (tid<256)

    // prologue: h(0)=0 in LDS buf0; x(0) packed in buf0; fp32 state zero
    sHfp[(tid >> 5)*33 + (tid & 31)] = 0.0f;
    { ull z = 0;
      *(ull*)(sH[0] + tid*32)      = z; *(ull*)(sH[0] + tid*32 + 8)  = z;
      *(ull*)(sH[0] + tid*32 + 16) = z; *(ull*)(sH[0] + tid*32 + 24) = z; }
    if (tid < 256){
        float4 f0 = *(const float4*)(src + ((size_t)(b0 + xrow)*TT + 0)*INW + xk);
        float4 f1 = *(const float4*)(src + ((size_t)(b0 + xrow)*TT + 0)*INW + xk + 4);
        bf16x8 v;
        v[0]=f2bf(f0.x); v[1]=f2bf(f0.y); v[2]=f2bf(f0.z); v[3]=f2bf(f0.w);
        v[4]=f2bf(f1.x); v[5]=f2bf(f1.y); v[6]=f2bf(f1.z); v[7]=f2bf(f1.w);
        *(bf16x8*)(sX[0] + xrow*256 + ((xk*2) ^ ((xrow & 7) << 4))) = v;
    }
    __syncthreads();

    for (int t = 0; t < TT; ++t){
        const int buf = t & 1, nbuf = buf ^ 1;
        const bool last = (t == TT-1);
        short* hdst = hbf + (size_t)nbuf * BB * EH;

        // ---- compute (r9-identical bodies) ----
        f32x4 acc0={0.f,0.f,0.f,0.f}, acc1={0.f,0.f,0.f,0.f}, accx={0.f,0.f,0.f,0.f};
        if (wid < 6){
            const int asw = (l15 & 7) << 4;
            const char* hb = sH[buf] + l15*1024;
            const char* xb = sX[buf] + l15*256;
            #pragma unroll
            for (int kt = 0; kt < 8; ++kt){ int kb = kt*64 + lk*16;
                acc0 = __builtin_amdgcn_mfma_f32_16x16x32_bf16(*(const bf16x8*)(hb+(kb^asw)), whB[kt], acc0, 0,0,0); }
            #pragma unroll
            for (int kt = 8; kt < 16; ++kt){ int kb = kt*64 + lk*16;
                acc1 = __builtin_amdgcn_mfma_f32_16x16x32_bf16(*(const bf16x8*)(hb+(kb^asw)), whB[kt], acc1, 0,0,0); }
            #pragma unroll
            for (int kt = 0; kt < 4; ++kt){ int kb = kt*64 + lk*16;
                accx = __builtin_amdgcn_mfma_f32_16x16x32_bf16(*(const bf16x8*)(xb+(kb^asw)), wxB[kt], accx, 0,0,0); }
        }
        f32x4 acch = acc0 + acc1;
        if (wid < 2){
            #pragma unroll
            for (int v = 0; v < 4; ++v) sR[(lk*4 + v)*33 + col] = sigm(accx[v] + acch[v]);
        } else if (wid < 4){
            #pragma unroll
            for (int v = 0; v < 4; ++v) sZ[(lk*4 + v)*33 + col] = sigm(accx[v] + acch[v]);
        }
        __syncthreads();   // mid: sR/sZ ready

        if (wid == 4 || wid == 5){   // n + combine + publish (dual store) + per-wave flag
            #pragma unroll
            for (int v = 0; v < 4; ++v){
                int row = lk*4 + v;
                float r  = sR[row*33 + col];
                float z  = sZ[row*33 + col];
                float n  = tanhf(accx[v] + r * acch[v]);
                float hp = sHfp[row*33 + col];
                float hn = (1.f - z)*n + z*hp;
                sHfp[row*33 + col] = hn;
                if (!last){
                    int gcol0 = j0 + ct*16 + (l15 & ~1);
                    pub_dual((unsigned*)&hdst[(size_t)(b0 + row)*EH + gcol0],
                             sH[nbuf], row, gcol0, (unsigned)(unsigned short)f2bf(hn), l15);
                } else {
                    hencf[(size_t)(b0 + row)*EH + j0 + col] = hn;
                }
            }
            if (!last){
                wave_drain();
                if (lane == 0) st_coh32(gf + (ng*2 + ct)*FLS, (unsigned)(t + 1));
            }
        } else if (wid < 4){          // x(t+1) load + pack into nbuf
            if (!last && tid < 256){
                float4 f0 = *(const float4*)(src + ((size_t)(b0 + xrow)*TT + (t+1))*INW + xk);
                float4 f1 = *(const float4*)(src + ((size_t)(b0 + xrow)*TT + (t+1))*INW + xk + 4);
                bf16x8 v;
                v[0]=f2bf(f0.x); v[1]=f2bf(f0.y); v[2]=f2bf(f0.z); v[3]=f2bf(f0.w);
                v[4]=f2bf(f1.x); v[5]=f2bf(f1.y); v[6]=f2bf(f1.z); v[7]=f2bf(f1.w);
                *(bf16x8*)(sX[nbuf] + xrow*256 + ((xk*2) ^ ((xrow & 7) << 4))) = v;
            }
        } else {                      // waves 6,7: stage h(t+1) as units arrive
            if (!last)
                stage_units(gf, (unsigned)(t + 1), (const char*)hdst, 1024,
                            sH[nbuf], b0, lane, (wid - 6)*16, ng);
        }
        __syncthreads();   // end: sH[nbuf], sX[nbuf] ready
    }
}

// ================= enc2gen linear + reparameterized IC sample =================================
__global__ __launch_bounds__(256) void ic_kernel(
    const float* __restrict__ henc,    // [256][512]
    const float* __restrict__ W,       // [1024][512]
    const float* __restrict__ eps,     // [256][512]
    float*       __restrict__ out_icp, // [256][1024] (output #2)
    float*       __restrict__ gh0f)    // [256][512] f32 generator IC
{
    __shared__ float hb[EH];
    const int b = blockIdx.x, tid = threadIdx.x;
    for (int k = tid; k < EH; k += 256) hb[k] = henc[(size_t)b*EH + k];
    __syncthreads();

    for (int jj = tid; jj < GH; jj += 256){
        const float4* wm = (const float4*)(W + (size_t)jj * EH);
        const float4* wl = (const float4*)(W + (size_t)(GH + jj) * EH);
        float am = 0.f, al = 0.f;
        #pragma unroll 4
        for (int k4 = 0; k4 < EH/4; ++k4){
            float4 h = ((const float4*)hb)[k4];
            float4 a = wm[k4], c = wl[k4];
            am += h.x*a.x + h.y*a.y + h.z*a.z + h.w*a.w;
            al += h.x*c.x + h.y*c.y + h.z*c.z + h.w*c.w;
        }
        out_icp[(size_t)b*2*GH + jj]      = am;
        out_icp[(size_t)b*2*GH + GH + jj] = al;
        gh0f[(size_t)b*GH + jj] = am + __expf(0.5f * al) * eps[(size_t)b*GH + jj];
    }
}

// ================= GENERATOR ===================================================================
__global__ __launch_bounds__(512, 1) void gen_kernel(
    const float* __restrict__ Wru,   // [1024][512] rows r then u
    const float* __restrict__ Wc,    // [512][512]
    const float* __restrict__ gh0f,  // [256][512] f32 ic
    short*       __restrict__ hbf,   // [2][256][512] bf16 ping-pong exchange
    short*       __restrict__ rhbf,  // [16][16][512] bf16 r*h exchange
    float*       __restrict__ out,   // [256][512][512] (output #1)
    unsigned*    __restrict__ rhFl,  // [16][32] x 64B
    unsigned*    __restrict__ hFl)   // [16][32] x 64B
{
    __shared__ __align__(16) char sH[MG*1024];    // h(t)   (single buffer — see sync proof)
    __shared__ __align__(16) char sRH[MG*1024];   // rh(t)
    __shared__ float sU[MG*33], sHfp[MG*33];

    const int bid = blockIdx.x, g = bid >> 4, ng = bid & 15;
    const int tid = threadIdx.x, wid = tid >> 6, lane = tid & 63;
    const int l15 = lane & 15, lk = lane >> 4;
    const int j0 = ng * NB, b0 = g * MG;
    const int gate = wid >> 1, ct = wid & 1, col = ct*16 + l15;
    unsigned* grf = rhFl + g * 32 * FLS;
    unsigned* ghf = hFl  + g * 32 * FLS;
    short* rhg = rhbf + (size_t)g * MG * GH;

    // persistent weights: waves 0,1 -> r; 2,3 -> u; 4,5 -> c
    bf16x8 wB[16];
    if (wid < 6){
        const float* wr;
        if (gate == 0)      wr = Wru + (size_t)(j0 + col) * GH;
        else if (gate == 1) wr = Wru + (size_t)(GH + j0 + col) * GH;
        else                wr = Wc  + (size_t)(j0 + col) * GH;
        #pragma unroll
        for (int kt = 0; kt < 16; ++kt){
            int ke = kt*32 + lk*8;
            float4 f0 = *(const float4*)(wr + ke);
            float4 f1 = *(const float4*)(wr + ke + 4);
            bf16x8 v;
            v[0]=f2bf(f0.x); v[1]=f2bf(f0.y); v[2]=f2bf(f0.z); v[3]=f2bf(f0.w);
            v[4]=f2bf(f1.x); v[5]=f2bf(f1.y); v[6]=f2bf(f1.z); v[7]=f2bf(f1.w);
            wB[kt] = v;
        }
    }

    // prologue: fp32 state + bf16 sH built locally from gh0f (no exchange)
    {
        int row = tid >> 5, c0 = (tid & 31) * 16;
        sHfp[row*33 + (tid & 31)] = gh0f[(size_t)(b0 + row)*GH + j0 + (tid & 31)];
        const float* sp = gh0f + (size_t)(b0 + row)*GH + c0;
        bf16x8 v0, v1;
        float4 a = *(const float4*)(sp),     b = *(const float4*)(sp + 4);
        float4 c = *(const float4*)(sp + 8), d = *(const float4*)(sp + 12);
        v0[0]=f2bf(a.x); v0[1]=f2bf(a.y); v0[2]=f2bf(a.z); v0[3]=f2bf(a.w);
        v0[4]=f2bf(b.x); v0[5]=f2bf(b.y); v0[6]=f2bf(b.z); v0[7]=f2bf(b.w);
        v1[0]=f2bf(c.x); v1[1]=f2bf(c.y); v1[2]=f2bf(c.z); v1[3]=f2bf(c.w);
        v1[4]=f2bf(d.x); v1[5]=f2bf(d.y); v1[6]=f2bf(d.z); v1[7]=f2bf(d.w);
        const int sw = (row & 7) << 4;
        int kb = c0 * 2;
        *(bf16x8*)(sH + row*1024 + ( kb       ^ sw)) = v0;
        *(bf16x8*)(sH + row*1024 + ((kb + 16) ^ sw)) = v1;
    }
    __syncthreads();

    for (int t = 0; t < TT; ++t){
        const bool last = (t == TT-1);
        const unsigned e = (unsigned)(t + 1);
        short* hdst = hbf + (size_t)((t + 1) & 1) * BB * GH;

        // ---- ph1: waves 0,1 r (publish rh, per-wave flag); 2,3 u; 6,7 stage rh ----
        if (wid < 4){
            const int asw = (l15 & 7) << 4;
            const char* hb = sH + l15*1024;
            f32x4 a0={0.f,0.f,0.f,0.f}, a1={0.f,0.f,0.f,0.f};
            #pragma unroll
            for (int kt = 0; kt < 8; ++kt){ int kb = kt*64 + lk*16;
                a0 = __builtin_amdgcn_mfma_f32_16x16x32_bf16(*(const bf16x8*)(hb+(kb^asw)), wB[kt], a0, 0,0,0); }
            #pragma unroll
            for (int kt = 8; kt < 16; ++kt){ int kb = kt*64 + lk*16;
                a1 = __builtin_amdgcn_mfma_f32_16x16x32_bf16(*(const bf16x8*)(hb+(kb^asw)), wB[kt], a1, 0,0,0); }
            f32x4 acc = a0 + a1;
            if (wid < 2){
                #pragma unroll
                for (int v = 0; v < 4; ++v){
                    int row = lk*4 + v;
                    float hp = sHfp[row*33 + col];
                    int gcol0 = j0 + ct*16 + (l15 & ~1);
                    pub_dual((unsigned*)&rhg[(size_t)row*GH + gcol0],
                             sRH, row, gcol0,
                             (unsigned)(unsigned short)f2bf(sigm(acc[v]) * hp), l15);
                }
                wave_drain();
                if (lane == 0) st_coh32(grf + (ng*2 + ct)*FLS, e);
            } else {
                #pragma unroll
                for (int v = 0; v < 4; ++v)
                    sU[(lk*4 + v)*33 + col] = sigm(acc[v] + 1.0f);
            }
        } else if (wid >= 6){
            stage_units(grf, e, (const char*)rhg, 1024, sRH, 0, lane, (wid - 6)*16, ng);
        }
        __syncthreads();   // mid: sRH + sU complete

        // ---- ph2: waves 4,5 c + combine + publish h(t+1); 6,7 stage h(t+1) ----
        if (wid == 4 || wid == 5){
            const int asw = (l15 & 7) << 4;
            const char* hb = sRH + l15*1024;
            f32x4 a0={0.f,0.f,0.f,0.f}, a1={0.f,0.f,0.f,0.f};
            #pragma unroll
            for (int kt = 0; kt < 8; ++kt){ int kb = kt*64 + lk*16;
                a0 = __builtin_amdgcn_mfma_f32_16x16x32_bf16(*(const bf16x8*)(hb+(kb^asw)), wB[kt], a0, 0,0,0); }
            #pragma unroll
            for (int kt = 8; kt < 16; ++kt){ int kb = kt*64 + lk*16;
                a1 = __builtin_amdgcn_mfma_f32_16x16x32_bf16(*(const bf16x8*)(hb+(kb^asw)), wB[kt], a1, 0,0,0); }
            f32x4 acc = a0 + a1;
            float hv[4];
            #pragma unroll
            for (int v = 0; v < 4; ++v){
                int row = lk*4 + v;
                float cv = tanhf(acc[v]);
                float u  = sU[row*33 + col];
                float hp = sHfp[row*33 + col];
                float hn = u*hp + (1.f - u)*cv;
                sHfp[row*33 + col] = hn;
                hv[v] = hn;
                if (!last){
                    int gcol0 = j0 + ct*16 + (l15 & ~1);
                    pub_dual((unsigned*)&hdst[(size_t)(b0 + row)*GH + gcol0],
                             sH, row, gcol0, (unsigned)(unsigned short)f2bf(hn), l15);
                }
            }
            if (!last){
                wave_drain();
                if (lane == 0) st_coh32(ghf + (ng*2 + ct)*FLS, e);
            }
            // deferred out[] stores: after the flag; next step's drain covers them
            #pragma unroll
            for (int v = 0; v < 4; ++v){
                int row = lk*4 + v;
                out[((size_t)(b0 + row)*TT + t)*GH + j0 + col] =
                    fminf(fmaxf(hv[v], -5.0f), 5.0f);
            }
        } else if (wid >= 6){
            if (!last)
                stage_units(ghf, e, (const char*)hdst, 1024, sH, b0, lane, (wid - 6)*16, ng);
        }
        __syncthreads();   // end: sH = h(t+1) ready
    }
}

extern "C" void kernel_launch(void* const* d_in, const int* in_sizes, int n_in,
                              void* d_out, int out_size, void* d_ws, size_t ws_size,
                              hipStream_t stream) {
    (void)in_sizes; (void)n_in; (void)out_size; (void)ws_size;

    const float* src    = (const float*)d_in[0];
    const float* eps    = (const float*)d_in[1];
    const float* enc_Wi = (const float*)d_in[2];
    const float* enc_Wh = (const float*)d_in[3];
    const float* e2g    = (const float*)d_in[4];
    const float* gWru   = (const float*)d_in[5];
    const float* gWc    = (const float*)d_in[6];
    float* out = (float*)d_out;

    // workspace layout (~2.45 MB):
    char* ws = (char*)d_ws;
    unsigned* encFl   = (unsigned*)ws;                       // 32 KB: 16 grp x 32 units x 64B
    unsigned* genRhFl = (unsigned*)(ws + 32768);             // 32 KB
    unsigned* genHFl  = (unsigned*)(ws + 65536);             // 32 KB
    float* hencf = (float*)(ws + 131072);                    // 512 KB [256][512] f32
    float* gh0f  = (float*)(ws + 131072 + 512*1024);         // 512 KB
    short* encH  = (short*)(ws + 131072 + 1024*1024);        // 512 KB [2][256][512] bf16
    short* genH  = (short*)(ws + 131072 + 1536*1024);        // 512 KB
    short* rhbf  = (short*)(ws + 131072 + 2048*1024);        // 256 KB [16][16][512] bf16

    hipMemsetAsync(ws, 0, 98304, stream);                    // all flag arrays = 0

    enc_kernel<<<dim3(256), dim3(512), 0, stream>>>(src, enc_Wi, enc_Wh, encH, hencf, encFl);
    ic_kernel <<<dim3(256), dim3(256), 0, stream>>>(hencf, e2g, eps,
                                                    out + (size_t)BB*TT*GH, gh0f);
    gen_kernel<<<dim3(256), dim3(512), 0, stream>>>(gWru, gWc, gh0f, genH, rhbf, out,
                                                    genRhFl, genHFl);
}

// Round 12
// 6534.019 us; speedup vs baseline: 2.0665x; 2.0665x over previous
//
#include <hip/hip_runtime.h>
#include <hip/hip_bf16.h>
#include <math.h>

#define BB 256
#define TT 512
#define INW 128
#define EH 512
#define GH 512

#define NGB 16           // blocks per group (column slices)
#define MGH 8            // batch rows per multiplexed group
#define NB 32            // output cols per block (2 x 16-col tiles)
#define FLS 16           // flag stride in u32 (64 B)

typedef __attribute__((ext_vector_type(8))) short bf16x8;
typedef __attribute__((ext_vector_type(4))) float f32x4;
typedef __attribute__((ext_vector_type(2))) unsigned long long u64x2;
typedef __attribute__((ext_vector_type(4))) unsigned int u32x4;
typedef unsigned long long ull;

__device__ __forceinline__ float sigm(float x){ return 1.0f/(1.0f+__expf(-x)); }
__device__ __forceinline__ short f2bf(float x){
    __hip_bfloat16 h = __float2bfloat16(x);
    return *reinterpret_cast<short*>(&h);
}

// IC-coherent (agent-scope, relaxed) ops — proven r3/r4/r9 path
__device__ __forceinline__ ull ld_coh64(const ull* p){
    return __hip_atomic_load(p, __ATOMIC_RELAXED, __HIP_MEMORY_SCOPE_AGENT);
}
__device__ __forceinline__ void st_coh32(unsigned* p, unsigned v){
    __hip_atomic_store(p, v, __ATOMIC_RELAXED, __HIP_MEMORY_SCOPE_AGENT);
}
__device__ __forceinline__ unsigned ld_flag(const unsigned* p){
    return __hip_atomic_load(p, __ATOMIC_RELAXED, __HIP_MEMORY_SCOPE_AGENT);
}
__device__ __forceinline__ void wave_drain(){ asm volatile("s_waitcnt vmcnt(0)" ::: "memory"); }

// parallel poll of 32 per-wave flags (2 lanes per flag), r9-style
__device__ __forceinline__ void poll32(const unsigned* gf, unsigned e){
    if (threadIdx.x < 64){
        const unsigned* p = gf + (threadIdx.x & 31) * FLS;
        long spins = 0;
        for(;;){
            unsigned v = ld_flag(p);
            if (__all((int)(v >= e))) break;
            if (++spins > (1L << 20)) break;   // escape hatch
        }
    }
}

// pack lane-pair bf16 -> u32, even lane stores coherently
__device__ __forceinline__ void pack_store_bf(unsigned* dst_even, short bv, int l15){
    unsigned mine = (unsigned short)bv;
    unsigned othr = __shfl_xor(mine, 1);
    if (!(l15 & 1)) st_coh32(dst_even, (othr << 16) | mine);
}

__device__ __forceinline__ bf16x8 packbf8(float4 f0, float4 f1){
    bf16x8 v;
    v[0]=f2bf(f0.x); v[1]=f2bf(f0.y); v[2]=f2bf(f0.z); v[3]=f2bf(f0.w);
    v[4]=f2bf(f1.x); v[5]=f2bf(f1.y); v[6]=f2bf(f1.z); v[7]=f2bf(f1.w);
    return v;
}

// x staging: one wave stages a group's [8][128] x-tile for step t (16 floats/lane)
__device__ __forceinline__ void stage_x(const float* src, char* sXdst, int b0,
                                        int lane, int t){
    int row = lane >> 3, kf = (lane & 7) * 16;
    const float* sp = src + ((size_t)(b0 + row)*TT + t)*INW + kf;
    float4 f0 = *(const float4*)sp,       f1 = *(const float4*)(sp + 4);
    float4 f2 = *(const float4*)(sp + 8), f3 = *(const float4*)(sp + 12);
    int kb = kf*2;
    const int sw = (row & 7) << 4;
    *(bf16x8*)(sXdst + row*256 + ( kb       ^ sw)) = packbf8(f0, f1);
    *(bf16x8*)(sXdst + row*256 + ((kb + 16) ^ sw)) = packbf8(f2, f3);
}

// ---------------- encoder one GRU step for one 8-row group (r6/r9-verified math) --------------
__device__ __forceinline__ void enc_phase(
    const char* sH, const char* sX, float* sR, float* sZ, float* sHfp,
    const bf16x8* whB, const bf16x8* wxB,
    short* hdst, float* hencf, unsigned* gf, unsigned e,
    int b0, int ng, int j0, int wid, int lane, int l15, int lk, int ct, int col,
    bool last)
{
    f32x4 acc0={0.f,0.f,0.f,0.f}, acc1={0.f,0.f,0.f,0.f}, accx={0.f,0.f,0.f,0.f};
    if (wid < 6){
        const int r8 = l15 & 7, asw = r8 << 4;
        const char* hb = sH + r8*1024;
        const char* xb = sX + r8*256;
        #pragma unroll
        for (int kt = 0; kt < 8; ++kt){ int kb = kt*64 + lk*16;
            acc0 = __builtin_amdgcn_mfma_f32_16x16x32_bf16(*(const bf16x8*)(hb+(kb^asw)), whB[kt], acc0, 0,0,0); }
        #pragma unroll
        for (int kt = 8; kt < 16; ++kt){ int kb = kt*64 + lk*16;
            acc1 = __builtin_amdgcn_mfma_f32_16x16x32_bf16(*(const bf16x8*)(hb+(kb^asw)), whB[kt], acc1, 0,0,0); }
        #pragma unroll
        for (int kt = 0; kt < 4; ++kt){ int kb = kt*64 + lk*16;
            accx = __builtin_amdgcn_mfma_f32_16x16x32_bf16(*(const bf16x8*)(xb+(kb^asw)), wxB[kt], accx, 0,0,0); }
    }
    f32x4 acch = acc0 + acc1;
    if (wid < 2){
        #pragma unroll
        for (int v = 0; v < 4; ++v){ int row = lk*4 + v;
            if (row < MGH) sR[row*33 + col] = sigm(accx[v] + acch[v]); }
    } else if (wid < 4){
        #pragma unroll
        for (int v = 0; v < 4; ++v){ int row = lk*4 + v;
            if (row < MGH) sZ[row*33 + col] = sigm(accx[v] + acch[v]); }
    }
    __syncthreads();
    if (wid == 4 || wid == 5){
        #pragma unroll
        for (int v = 0; v < 4; ++v){ int row = lk*4 + v;
            if (row < MGH){
                float r  = sR[row*33 + col];
                float z  = sZ[row*33 + col];
                float n  = tanhf(accx[v] + r * acch[v]);
                float hp = sHfp[row*33 + col];
                float hn = (1.f - z)*n + z*hp;
                sHfp[row*33 + col] = hn;
                if (!last)
                    pack_store_bf((unsigned*)&hdst[(size_t)(b0+row)*EH + j0 + ct*16 + (l15 & ~1)],
                                  f2bf(hn), l15);
                else
                    hencf[(size_t)(b0+row)*EH + j0 + col] = hn;
            }
        }
        if (!last){
            wave_drain();
            if (lane == 0) st_coh32(gf + (ng*2 + ct)*FLS, e);   // per-wave flag
        }
    }
}

// ---------------- generator phase 1 (r,u) for one group ---------------------------------------
__device__ __forceinline__ void gen_ph1(
    const char* sH, float* sU, const float* sHfp, const bf16x8* wB,
    short* rhg, unsigned* gf, unsigned e,
    int ng, int j0, int wid, int lane, int l15, int lk, int ct, int col)
{
    if (wid < 4){
        const int r8 = l15 & 7, asw = r8 << 4;
        const char* hb = sH + r8*1024;
        f32x4 a0={0.f,0.f,0.f,0.f}, a1={0.f,0.f,0.f,0.f};
        #pragma unroll
        for (int kt = 0; kt < 8; ++kt){ int kb = kt*64 + lk*16;
            a0 = __builtin_amdgcn_mfma_f32_16x16x32_bf16(*(const bf16x8*)(hb+(kb^asw)), wB[kt], a0, 0,0,0); }
        #pragma unroll
        for (int kt = 8; kt < 16; ++kt){ int kb = kt*64 + lk*16;
            a1 = __builtin_amdgcn_mfma_f32_16x16x32_bf16(*(const bf16x8*)(hb+(kb^asw)), wB[kt], a1, 0,0,0); }
        f32x4 acc = a0 + a1;
        if (wid < 2){
            #pragma unroll
            for (int v = 0; v < 4; ++v){ int row = lk*4 + v;
                if (row < MGH){
                    float hp = sHfp[row*33 + col];
                    pack_store_bf((unsigned*)&rhg[(size_t)row*GH + j0 + ct*16 + (l15 & ~1)],
                                  f2bf(sigm(acc[v]) * hp), l15);
                }}
            wave_drain();
            if (lane == 0) st_coh32(gf + (ng*2 + ct)*FLS, e);
        } else {
            #pragma unroll
            for (int v = 0; v < 4; ++v){ int row = lk*4 + v;
                if (row < MGH) sU[row*33 + col] = sigm(acc[v] + 1.0f); }
        }
    }
}

// ---------------- generator phase 2 (c, combine) for one group --------------------------------
__device__ __forceinline__ void gen_ph2(
    const char* sRH, const float* sU, float* sHfp, const bf16x8* wB,
    short* hdst, unsigned* gf, unsigned e, float* out, int t,
    int b0, int ng, int j0, int wid, int lane, int l15, int lk, int ct, int col,
    bool last)
{
    if (wid == 4 || wid == 5){
        const int r8 = l15 & 7, asw = r8 << 4;
        const char* hb = sRH + r8*1024;
        f32x4 a0={0.f,0.f,0.f,0.f}, a1={0.f,0.f,0.f,0.f};
        #pragma unroll
        for (int kt = 0; kt < 8; ++kt){ int kb = kt*64 + lk*16;
            a0 = __builtin_amdgcn_mfma_f32_16x16x32_bf16(*(const bf16x8*)(hb+(kb^asw)), wB[kt], a0, 0,0,0); }
        #pragma unroll
        for (int kt = 8; kt < 16; ++kt){ int kb = kt*64 + lk*16;
            a1 = __builtin_amdgcn_mfma_f32_16x16x32_bf16(*(const bf16x8*)(hb+(kb^asw)), wB[kt], a1, 0,0,0); }
        f32x4 acc = a0 + a1;
        float hv[4];
        #pragma unroll
        for (int v = 0; v < 4; ++v){ int row = lk*4 + v;
            if (row < MGH){
                float cv = tanhf(acc[v]);
                float u  = sU[row*33 + col];
                float hp = sHfp[row*33 + col];
                float hn = u*hp + (1.f - u)*cv;
                sHfp[row*33 + col] = hn;
                hv[v] = hn;
                if (!last)
                    pack_store_bf((unsigned*)&hdst[(size_t)(b0+row)*GH + j0 + ct*16 + (l15 & ~1)],
                                  f2bf(hn), l15);
            }
        }
        if (!last){
            wave_drain();
            if (lane == 0) st_coh32(gf + (ng*2 + ct)*FLS, e);
        }
        // deferred out stores: after the flag; drained by next wave_drain / kernel end
        #pragma unroll
        for (int v = 0; v < 4; ++v){ int row = lk*4 + v;
            if (row < MGH)
                out[((size_t)(b0+row)*TT + t)*GH + j0 + col] =
                    fminf(fmaxf(hv[v], -5.f), 5.f);
        }
    }
}

// ================= ENCODER: 2-group multiplex, flag -> other-compute -> poll ===================
__global__ __launch_bounds__(512, 1) void enc_kernel(
    const float* __restrict__ src,   // [256][512][128]
    const float* __restrict__ Wi,    // [1536][128] rows r,z,n
    const float* __restrict__ Wh,    // [1536][512]
    short*       __restrict__ hbf,   // [2][256][512] bf16 ping-pong exchange
    float*       __restrict__ hencf, // [256][512] f32 final state
    unsigned*    __restrict__ flA,   // [16 pr][32] x 64B
    unsigned*    __restrict__ flB)
{
    __shared__ __align__(16) char sHA[MGH*1024], sHB[MGH*1024];
    __shared__ __align__(16) char sXA[2][MGH*256], sXB[2][MGH*256];
    __shared__ float sRA[MGH*33], sZA[MGH*33], sRB[MGH*33], sZB[MGH*33];
    __shared__ float sHfpA[MGH*33], sHfpB[MGH*33];

    const int bid = blockIdx.x, pr = bid >> 4, ng = bid & 15;
    const int tid = threadIdx.x, wid = tid >> 6, lane = tid & 63;
    const int l15 = lane & 15, lk = lane >> 4;
    const int j0 = ng * NB;
    const int b0A = pr*16, b0B = pr*16 + 8;
    const int gate = wid >> 1, ct = wid & 1, col = ct*16 + l15;
    unsigned* gfA = flA + pr * 32 * FLS;
    unsigned* gfB = flB + pr * 32 * FLS;

    // persistent weights (r9-verified loader), shared by groups A and B
    bf16x8 whB[16], wxB[4];
    if (wid < 6){
        const float* wrh = Wh + (size_t)(gate*EH + j0 + col) * EH;
        const float* wrx = Wi + (size_t)(gate*EH + j0 + col) * INW;
        #pragma unroll
        for (int kt = 0; kt < 16; ++kt){
            int ke = kt*32 + lk*8;
            float4 f0 = *(const float4*)(wrh + ke);
            float4 f1 = *(const float4*)(wrh + ke + 4);
            whB[kt] = packbf8(f0, f1);
        }
        #pragma unroll
        for (int kt = 0; kt < 4; ++kt){
            int ke = kt*32 + lk*8;
            float4 f0 = *(const float4*)(wrx + ke);
            float4 f1 = *(const float4*)(wrx + ke + 4);
            wxB[kt] = packbf8(f0, f1);
        }
    }

    // prologue: h(0)=0 in LDS; fp32 state zero; x(0) packed into buf 0
    { u32x4 z = {0,0,0,0};
      *(u32x4*)(sHA + tid*16) = z;
      *(u32x4*)(sHB + tid*16) = z; }
    if (tid < MGH*33){ sHfpA[tid] = 0.f; sHfpB[tid] = 0.f; }
    if (wid == 6) stage_x(src, sXA[0], b0A, lane, 0);
    if (wid == 7) stage_x(src, sXB[0], b0B, lane, 0);
    __syncthreads();

    for (int t = 0; t < TT; ++t){
        const int buf = t & 1, nbuf = buf ^ 1;
        const bool last = (t == TT-1);
        const unsigned e = (unsigned)(t + 1);
        short* hdst = hbf + (size_t)nbuf * BB * EH;

        // waves 6,7: x(t+1) -> sX[nbuf] (concurrent with compute below)
        if (!last){
            if (wid == 6) stage_x(src, sXA[nbuf], b0A, lane, t+1);
            if (wid == 7) stage_x(src, sXB[nbuf], b0B, lane, t+1);
        }

        // group A step t: compute + publish + per-wave flags
        enc_phase(sHA, sXA[buf], sRA, sZA, sHfpA, whB, wxB, hdst, hencf,
                  gfA, e, b0A, ng, j0, wid, lane, l15, lk, ct, col, last);
        // group B step t (flag A propagates during this)
        enc_phase(sHB, sXB[buf], sRB, sZB, sHfpB, whB, wxB, hdst, hencf,
                  gfB, e, b0B, ng, j0, wid, lane, l15, lk, ct, col, last);

        if (!last){
            poll32(gfA, e);
            __syncthreads();
            const int row = tid >> 6, kb = (tid & 63) << 4;
            const ull* gpA = (const ull*)((const char*)(hdst + (size_t)(b0A+row)*EH) + kb);
            ull a0 = ld_coh64(gpA), a1 = ld_coh64(gpA + 1);   // issue; flight overlaps poll B
            poll32(gfB, e);
            __syncthreads();
            { u64x2 v; v[0]=a0; v[1]=a1;
              *(u64x2*)(sHA + row*1024 + (kb ^ (row << 4))) = v; }
            const ull* gpB = (const ull*)((const char*)(hdst + (size_t)(b0B+row)*EH) + kb);
            ull c0 = ld_coh64(gpB), c1 = ld_coh64(gpB + 1);
            { u64x2 v; v[0]=c0; v[1]=c1;
              *(u64x2*)(sHB + row*1024 + (kb ^ (row << 4))) = v; }
        }
        __syncthreads();
    }
}

// ================= enc2gen linear + reparameterized IC sample =================================
__global__ __launch_bounds__(256) void ic_kernel(
    const float* __restrict__ henc,    // [256][512]
    const float* __restrict__ W,       // [1024][512]
    const float* __restrict__ eps,     // [256][512]
    float*       __restrict__ out_icp, // [256][1024] (output #2)
    float*       __restrict__ gh0f)    // [256][512] f32 generator IC
{
    __shared__ float hb[EH];
    const int b = blockIdx.x, tid = threadIdx.x;
    for (int k = tid; k < EH; k += 256) hb[k] = henc[(size_t)b*EH + k];
    __syncthreads();

    for (int jj = tid; jj < GH; jj += 256){
        const float4* wm = (const float4*)(W + (size_t)jj * EH);
        const float4* wl = (const float4*)(W + (size_t)(GH + jj) * EH);
        float am = 0.f, al = 0.f;
        #pragma unroll 4
        for (int k4 = 0; k4 < EH/4; ++k4){
            float4 h = ((const float4*)hb)[k4];
            float4 a = wm[k4], c = wl[k4];
            am += h.x*a.x + h.y*a.y + h.z*a.z + h.w*a.w;
            al += h.x*c.x + h.y*c.y + h.z*c.z + h.w*c.w;
        }
        out_icp[(size_t)b*2*GH + jj]      = am;
        out_icp[(size_t)b*2*GH + GH + jj] = al;
        gh0f[(size_t)b*GH + jj] = am + __expf(0.5f * al) * eps[(size_t)b*GH + jj];
    }
}

// ================= GENERATOR: 2-group multiplex, 2 phases each ================================
__global__ __launch_bounds__(512, 1) void gen_kernel(
    const float* __restrict__ Wru,   // [1024][512] rows r then u
    const float* __restrict__ Wc,    // [512][512]
    const float* __restrict__ gh0f,  // [256][512] f32 ic
    short*       __restrict__ hbf,   // [2][256][512] bf16 ping-pong exchange
    short*       __restrict__ rhbf,  // [16 pr][2][8][512] bf16 r*h exchange
    float*       __restrict__ out,   // [256][512][512] (output #1)
    unsigned*    __restrict__ rhFlA, unsigned* __restrict__ rhFlB,
    unsigned*    __restrict__ hFlA,  unsigned* __restrict__ hFlB)
{
    __shared__ __align__(16) char sHA[MGH*1024], sHB[MGH*1024];
    __shared__ __align__(16) char sRHA[MGH*1024], sRHB[MGH*1024];
    __shared__ float sUA[MGH*33], sUB[MGH*33], sHfpA[MGH*33], sHfpB[MGH*33];

    const int bid = blockIdx.x, pr = bid >> 4, ng = bid & 15;
    const int tid = threadIdx.x, wid = tid >> 6, lane = tid & 63;
    const int l15 = lane & 15, lk = lane >> 4;
    const int j0 = ng * NB;
    const int b0A = pr*16, b0B = pr*16 + 8;
    const int gate = wid >> 1, ct = wid & 1, col = ct*16 + l15;
    unsigned* grA = rhFlA + pr * 32 * FLS;
    unsigned* grB = rhFlB + pr * 32 * FLS;
    unsigned* ghA = hFlA  + pr * 32 * FLS;
    unsigned* ghB = hFlB  + pr * 32 * FLS;
    short* rhgA = rhbf + (size_t)(pr*2 + 0) * MGH * GH;
    short* rhgB = rhbf + (size_t)(pr*2 + 1) * MGH * GH;

    // persistent weights: waves 0,1 -> r; 2,3 -> u; 4,5 -> c (shared by A,B)
    bf16x8 wB[16];
    if (wid < 6){
        const float* wr;
        if (gate == 0)      wr = Wru + (size_t)(j0 + col) * GH;
        else if (gate == 1) wr = Wru + (size_t)(GH + j0 + col) * GH;
        else                wr = Wc  + (size_t)(j0 + col) * GH;
        #pragma unroll
        for (int kt = 0; kt < 16; ++kt){
            int ke = kt*32 + lk*8;
            float4 f0 = *(const float4*)(wr + ke);
            float4 f1 = *(const float4*)(wr + ke + 4);
            wB[kt] = packbf8(f0, f1);
        }
    }

    // prologue: fp32 state + bf16 sH tiles built locally from gh0f (no exchange)
    {
        int half = tid >> 8, tt = tid & 255;
        int row = tt >> 5, c0 = (tt & 31) * 16;
        int b0g = half ? b0B : b0A;
        char* sdst = half ? sHB : sHA;
        const float* sp = gh0f + (size_t)(b0g + row)*GH + c0;
        float4 a = *(const float4*)sp,        b = *(const float4*)(sp + 4);
        float4 c = *(const float4*)(sp + 8),  d = *(const float4*)(sp + 12);
        int kb = c0*2; const int sw = (row & 7) << 4;
        *(bf16x8*)(sdst + row*1024 + ( kb       ^ sw)) = packbf8(a, b);
        *(bf16x8*)(sdst + row*1024 + ((kb + 16) ^ sw)) = packbf8(c, d);
        if (half == 0) sHfpA[row*33 + (tt & 31)] = gh0f[(size_t)(b0A+row)*GH + j0 + (tt & 31)];
        else           sHfpB[row*33 + (tt & 31)] = gh0f[(size_t)(b0B+row)*GH + j0 + (tt & 31)];
    }
    __syncthreads();

    for (int t = 0; t < TT; ++t){
        const bool last = (t == TT-1);
        const unsigned e = (unsigned)(t + 1);
        short* hdst = hbf + (size_t)((t + 1) & 1) * BB * GH;

        // ph1 A then B (A's rh-flag propagates during B's compute)
        gen_ph1(sHA, sUA, sHfpA, wB, rhgA, grA, e, ng, j0, wid, lane, l15, lk, ct, col);
        gen_ph1(sHB, sUB, sHfpB, wB, rhgB, grB, e, ng, j0, wid, lane, l15, lk, ct, col);

        poll32(grA, e);
        __syncthreads();
        {
            const int row = tid >> 6, kb = (tid & 63) << 4;
            const ull* gpA = (const ull*)((const char*)(rhgA + (size_t)row*GH) + kb);
            ull a0 = ld_coh64(gpA), a1 = ld_coh64(gpA + 1);   // issue; overlaps poll B
            poll32(grB, e);
            __syncthreads();
            { u64x2 v; v[0]=a0; v[1]=a1;
              *(u64x2*)(sRHA + row*1024 + (kb ^ (row << 4))) = v; }
            const ull* gpB = (const ull*)((const char*)(rhgB + (size_t)row*GH) + kb);
            ull c0 = ld_coh64(gpB), c1 = ld_coh64(gpB + 1);
            { u64x2 v; v[0]=c0; v[1]=c1;
              *(u64x2*)(sRHB + row*1024 + (kb ^ (row << 4))) = v; }
        }
        __syncthreads();   // sRH A/B + sU A/B ready

        // ph2 A then B
        gen_ph2(sRHA, sUA, sHfpA, wB, hdst, ghA, e, out, t, b0A, ng, j0,
                wid, lane, l15, lk, ct, col, last);
        gen_ph2(sRHB, sUB, sHfpB, wB, hdst, ghB, e, out, t, b0B, ng, j0,
                wid, lane, l15, lk, ct, col, last);

        if (!last){
            poll32(ghA, e);
            __syncthreads();
            const int row = tid >> 6, kb = (tid & 63) << 4;
            const ull* gpA = (const ull*)((const char*)(hdst + (size_t)(b0A+row)*GH) + kb);
            ull a0 = ld_coh64(gpA), a1 = ld_coh64(gpA + 1);
            poll32(ghB, e);
            __syncthreads();
            { u64x2 v; v[0]=a0; v[1]=a1;
              *(u64x2*)(sHA + row*1024 + (kb ^ (row << 4))) = v; }
            const ull* gpB = (const ull*)((const char*)(hdst + (size_t)(b0B+row)*GH) + kb);
            ull c0 = ld_coh64(gpB), c1 = ld_coh64(gpB + 1);
            { u64x2 v; v[0]=c0; v[1]=c1;
              *(u64x2*)(sHB + row*1024 + (kb ^ (row << 4))) = v; }
        }
        __syncthreads();
    }
}

extern "C" void kernel_launch(void* const* d_in, const int* in_sizes, int n_in,
                              void* d_out, int out_size, void* d_ws, size_t ws_size,
                              hipStream_t stream) {
    (void)in_sizes; (void)n_in; (void)out_size; (void)ws_size;

    const float* src    = (const float*)d_in[0];
    const float* eps    = (const float*)d_in[1];
    const float* enc_Wi = (const float*)d_in[2];
    const float* enc_Wh = (const float*)d_in[3];
    const float* e2g    = (const float*)d_in[4];
    const float* gWru   = (const float*)d_in[5];
    const float* gWc    = (const float*)d_in[6];
    float* out = (float*)d_out;

    // workspace (~2.44 MB)
    char* ws = (char*)d_ws;
    unsigned* encFlA = (unsigned*)(ws);              // 32 KB each: [16 pr][32] x 64B
    unsigned* encFlB = (unsigned*)(ws + 32*1024);
    unsigned* rhFlA  = (unsigned*)(ws + 64*1024);
    unsigned* rhFlB  = (unsigned*)(ws + 96*1024);
    unsigned* hFlA   = (unsigned*)(ws + 128*1024);
    unsigned* hFlB   = (unsigned*)(ws + 160*1024);
    float* hencf = (float*)(ws + 192*1024);          // 512 KB
    float* gh0f  = (float*)(ws + 704*1024);          // 512 KB
    short* encH  = (short*)(ws + 1216*1024);         // 512 KB [2][256][512] bf16
    short* genH  = (short*)(ws + 1728*1024);         // 512 KB
    short* rhbf  = (short*)(ws + 2240*1024);         // 256 KB [16][2][8][512] bf16

    hipMemsetAsync(ws, 0, 192*1024, stream);         // all flag arrays = 0

    enc_kernel<<<dim3(256), dim3(512), 0, stream>>>(src, enc_Wi, enc_Wh, encH, hencf,
                                                    encFlA, encFlB);
    ic_kernel <<<dim3(256), dim3(256), 0, stream>>>(hencf, e2g, eps,
                                                    out + (size_t)BB*TT*GH, gh0f);
    gen_kernel<<<dim3(256), dim3(512), 0, stream>>>(gWru, gWc, gh0f, genH, rhbf, out,
                                                    rhFlA, rhFlB, hFlA, hFlB);
}